// Round 6
// baseline (1176.360 us; speedup 1.0000x reference)
//
#include <hip/hip_runtime.h>
#include <hip/hip_bf16.h>
#include <cstdint>

typedef __attribute__((ext_vector_type(8))) short short8v;
typedef __attribute__((ext_vector_type(4))) float f32x4;

__device__ __forceinline__ float4 add4(float4 a, float4 b) {
  return make_float4(a.x + b.x, a.y + b.y, a.z + b.z, a.w + b.w);
}
__device__ __forceinline__ float bf2f(unsigned short u) {
  union { unsigned int i; float f; } v; v.i = ((unsigned int)u) << 16; return v.f;
}
__device__ __forceinline__ unsigned short f2bf(float f) {
  union { float f; unsigned int i; } v; v.f = f;
  unsigned int r = v.i + 0x7fff + ((v.i >> 16) & 1);
  return (unsigned short)(r >> 16);
}

// route v (belonging to CSR position p) into the accumulator of its node (4 nodes/block)
__device__ __forceinline__ void pacc4(int p, int b1, int b2, int b3, float4 v,
                                      float4& a0, float4& a1, float4& a2, float4& a3) {
  if (p < b2) { if (p < b1) a0 = add4(a0, v); else a1 = add4(a1, v); }
  else        { if (p < b3) a2 = add4(a2, v); else a3 = add4(a3, v); }
}
__device__ __forceinline__ void pacc8(int p, int b1, int b2, int b3, const float (&f)[8],
                                      float (&a0)[8], float (&a1)[8], float (&a2)[8], float (&a3)[8]) {
  if (p < b2) {
    if (p < b1) {
#pragma unroll
      for (int j = 0; j < 8; ++j) a0[j] += f[j];
    } else {
#pragma unroll
      for (int j = 0; j < 8; ++j) a1[j] += f[j];
    }
  } else {
    if (p < b3) {
#pragma unroll
      for (int j = 0; j < 8; ++j) a2[j] += f[j];
    } else {
#pragma unroll
      for (int j = 0; j < 8; ++j) a3[j] += f[j];
    }
  }
}

// ---------------- CSR build ----------------

__global__ void count_deg_kernel(const int* __restrict__ dst, int* __restrict__ deg, int E) {
  int i = blockIdx.x * blockDim.x + threadIdx.x;
  if (i < E) atomicAdd(&deg[dst[i]], 1);
}

__global__ void block_sum_kernel(const int* __restrict__ deg, int* __restrict__ bsum, int N) {
  int t = threadIdx.x;
  int i = blockIdx.x * 512 + t;
  int v = (i < N) ? deg[i] : 0;
#pragma unroll
  for (int off = 32; off > 0; off >>= 1) v += __shfl_down(v, off, 64);
  __shared__ int ws[8];
  int lane = t & 63, wid = t >> 6;
  if (lane == 0) ws[wid] = v;
  __syncthreads();
  if (t == 0) {
    int s = 0;
#pragma unroll
    for (int j = 0; j < 8; ++j) s += ws[j];
    bsum[blockIdx.x] = s;
  }
}

__global__ void scan_small_kernel(const int* __restrict__ bsum, int* __restrict__ boffs, int B) {
  int t = threadIdx.x;
  int lane = t & 63, wid = t >> 6;
  int v = (t < B) ? bsum[t] : 0;
  int incl = v;
#pragma unroll
  for (int off = 1; off < 64; off <<= 1) {
    int u = __shfl_up(incl, off, 64);
    if (lane >= off) incl += u;
  }
  __shared__ int ws[2];
  if (lane == 63) ws[wid] = incl;
  __syncthreads();
  int base = (wid == 1) ? ws[0] : 0;
  if (t < B) boffs[t] = base + incl - v;
}

__global__ void ptrs_kernel(const int* __restrict__ deg, const int* __restrict__ boffs,
                            int* __restrict__ ptrs, int N) {
  int t = threadIdx.x;
  int i = blockIdx.x * 512 + t;
  int lane = t & 63, wid = t >> 6;
  int v = (i < N) ? deg[i] : 0;
  int incl = v;
#pragma unroll
  for (int off = 1; off < 64; off <<= 1) {
    int u = __shfl_up(incl, off, 64);
    if (lane >= off) incl += u;
  }
  __shared__ int ws[8];
  if (lane == 63) ws[wid] = incl;
  __syncthreads();
  if (t == 0) {
    int s = 0;
#pragma unroll
    for (int j = 0; j < 8; ++j) { int tmp = ws[j]; ws[j] = s; s += tmp; }
  }
  __syncthreads();
  if (i < N) ptrs[i + 1] = boffs[blockIdx.x] + ws[wid] + incl;
  if (i == 0 && blockIdx.x == 0) ptrs[0] = 0;
}

__global__ void fill_csr_kernel(const int* __restrict__ src, const int* __restrict__ dst,
                                const int* __restrict__ ptrs, int* __restrict__ cnt,
                                int2* __restrict__ csr, int E) {
  int i = blockIdx.x * blockDim.x + threadIdx.x;
  if (i < E) {
    int d = dst[i];
    int pos = ptrs[d] + atomicAdd(&cnt[d], 1);
    csr[pos] = make_int2(src[i], i);
  }
}

// ---------------- conversions ----------------

__global__ void f2bf_stream_kernel(const float* __restrict__ in, unsigned short* __restrict__ out, int n) {
  int i = (blockIdx.x * blockDim.x + threadIdx.x) * 8;
  if (i < n) {
    float4 v0 = *(const float4*)(in + i);
    float4 v1 = *(const float4*)(in + i + 4);
    short8v o;
    o[0] = (short)f2bf(v0.x); o[1] = (short)f2bf(v0.y);
    o[2] = (short)f2bf(v0.z); o[3] = (short)f2bf(v0.w);
    o[4] = (short)f2bf(v1.x); o[5] = (short)f2bf(v1.y);
    o[6] = (short)f2bf(v1.z); o[7] = (short)f2bf(v1.w);
    *(short8v*)(out + i) = o;
  }
}

// pack all three layers' weights: Wt[c][k] = (k<rowsE ? We[k][c] : Wr[k-rowsE][c]) bf16
__global__ void pack_all_kernel(const float* __restrict__ We0, const float* __restrict__ Wr0,
                                const float* __restrict__ We1, const float* __restrict__ Wr1,
                                const float* __restrict__ We2, const float* __restrict__ Wr2,
                                unsigned short* __restrict__ Wt0, unsigned short* __restrict__ Wt1,
                                unsigned short* __restrict__ Wt2) {
  int idx = blockIdx.x * blockDim.x + threadIdx.x;
  const float* We; const float* Wr; unsigned short* Wt;
  int rowsE, Ktot, local;
  if (idx < 128 * 192) {
    We = We0; Wr = Wr0; Wt = Wt0; rowsE = 128; Ktot = 192; local = idx;
  } else if (idx < 128 * 192 + 128 * 320) {
    We = We1; Wr = Wr1; Wt = Wt1; rowsE = 192; Ktot = 320; local = idx - 128 * 192;
  } else if (idx < 128 * 192 + 2 * 128 * 320) {
    We = We2; Wr = Wr2; Wt = Wt2; rowsE = 192; Ktot = 320; local = idx - 128 * 192 - 128 * 320;
  } else {
    return;
  }
  int c = local / Ktot, k = local % Ktot;
  float v = (k < rowsE) ? We[(size_t)k * 128 + c] : Wr[(size_t)(k - rowsE) * 128 + c];
  Wt[local] = f2bf(v);
}

// ---------------- Aggregation: 4 nodes per block, deep-pipelined gathers ----------------

// edge_attr aggregate: fp32 rows of 64 (256B), 16 lanes/row, 16 slots, unroll 2.
__global__ __launch_bounds__(256) void agg_ea_kernel(
    const int* __restrict__ ptrs, const int2* __restrict__ csr,
    const float* __restrict__ ea, unsigned short* __restrict__ agge, int N) {
  int n0 = blockIdx.x * 4;
  int t = threadIdx.x;
  int slot = t >> 4, cg = t & 15;
  int b0 = ptrs[n0];
  int b1 = ptrs[min(n0 + 1, N)];
  int b2 = ptrs[min(n0 + 2, N)];
  int b3 = ptrs[min(n0 + 3, N)];
  int b4 = ptrs[min(n0 + 4, N)];
  float4 z = make_float4(0, 0, 0, 0);
  float4 a0 = z, a1 = z, a2 = z, a3 = z;
  int i = b0 + slot;
  for (; i + 16 < b4; i += 32) {
    int e0 = csr[i].y, e1 = csr[i + 16].y;
    float4 v0 = *((const float4*)(ea + (size_t)e0 * 64) + cg);
    float4 v1 = *((const float4*)(ea + (size_t)e1 * 64) + cg);
    pacc4(i, b1, b2, b3, v0, a0, a1, a2, a3);
    pacc4(i + 16, b1, b2, b3, v1, a0, a1, a2, a3);
  }
  if (i < b4) {
    int e0 = csr[i].y;
    float4 v0 = *((const float4*)(ea + (size_t)e0 * 64) + cg);
    pacc4(i, b1, b2, b3, v0, a0, a1, a2, a3);
  }
  __shared__ float red[16][4][64];
  *(float4*)&red[slot][0][cg * 4] = a0;
  *(float4*)&red[slot][1][cg * 4] = a1;
  *(float4*)&red[slot][2][cg * 4] = a2;
  *(float4*)&red[slot][3][cg * 4] = a3;
  __syncthreads();
  int nd = t >> 6, col = t & 63;
  float s = 0.f;
#pragma unroll
  for (int r = 0; r < 16; ++r) s += red[r][nd][col];
  int n = n0 + nd;
  if (n < N) agge[(size_t)n * 64 + col] = f2bf(s);
}

// bf16 rows of 64 (128B), 8 lanes/row, 32 slots.
__global__ __launch_bounds__(256) void agg_bf64_kernel(
    const int* __restrict__ ptrs, const int2* __restrict__ csr,
    const unsigned short* __restrict__ xb, unsigned short* __restrict__ outagg, int N) {
  int n0 = blockIdx.x * 4;
  int t = threadIdx.x;
  int slot = t >> 3, cg = t & 7;
  int b0 = ptrs[n0];
  int b1 = ptrs[min(n0 + 1, N)];
  int b2 = ptrs[min(n0 + 2, N)];
  int b3 = ptrs[min(n0 + 3, N)];
  int b4 = ptrs[min(n0 + 4, N)];
  float a0[8], a1[8], a2[8], a3[8];
#pragma unroll
  for (int j = 0; j < 8; ++j) { a0[j] = 0.f; a1[j] = 0.f; a2[j] = 0.f; a3[j] = 0.f; }
  for (int i = b0 + slot; i < b4; i += 32) {
    int r = csr[i].x;
    short8v v = *(const short8v*)(xb + (size_t)r * 64 + cg * 8);
    float f[8];
#pragma unroll
    for (int j = 0; j < 8; ++j) f[j] = bf2f((unsigned short)v[j]);
    pacc8(i, b1, b2, b3, f, a0, a1, a2, a3);
  }
  __shared__ float red[32][4][64];
#pragma unroll
  for (int j = 0; j < 8; ++j) {
    red[slot][0][cg * 8 + j] = a0[j];
    red[slot][1][cg * 8 + j] = a1[j];
    red[slot][2][cg * 8 + j] = a2[j];
    red[slot][3][cg * 8 + j] = a3[j];
  }
  __syncthreads();
  int nd = t >> 6, col = t & 63;
  float s = 0.f;
#pragma unroll
  for (int r = 0; r < 32; ++r) s += red[r][nd][col];
  int n = n0 + nd;
  if (n < N) outagg[(size_t)n * 64 + col] = f2bf(s);
}

// bf16 rows of 128 (256B), 16 lanes/row, 16 slots, unroll 2.
__global__ __launch_bounds__(256) void agg_bf128_kernel(
    const int* __restrict__ ptrs, const int2* __restrict__ csr,
    const unsigned short* __restrict__ xb, unsigned short* __restrict__ outagg, int N) {
  int n0 = blockIdx.x * 4;
  int t = threadIdx.x;
  int slot = t >> 4, cg = t & 15;
  int b0 = ptrs[n0];
  int b1 = ptrs[min(n0 + 1, N)];
  int b2 = ptrs[min(n0 + 2, N)];
  int b3 = ptrs[min(n0 + 3, N)];
  int b4 = ptrs[min(n0 + 4, N)];
  float a0[8], a1[8], a2[8], a3[8];
#pragma unroll
  for (int j = 0; j < 8; ++j) { a0[j] = 0.f; a1[j] = 0.f; a2[j] = 0.f; a3[j] = 0.f; }
  int i = b0 + slot;
  for (; i + 16 < b4; i += 32) {
    int r0 = csr[i].x, r1 = csr[i + 16].x;
    short8v v0 = *(const short8v*)(xb + (size_t)r0 * 128 + cg * 8);
    short8v v1 = *(const short8v*)(xb + (size_t)r1 * 128 + cg * 8);
    float f0[8], f1[8];
#pragma unroll
    for (int j = 0; j < 8; ++j) { f0[j] = bf2f((unsigned short)v0[j]); f1[j] = bf2f((unsigned short)v1[j]); }
    pacc8(i, b1, b2, b3, f0, a0, a1, a2, a3);
    pacc8(i + 16, b1, b2, b3, f1, a0, a1, a2, a3);
  }
  if (i < b4) {
    int r0 = csr[i].x;
    short8v v0 = *(const short8v*)(xb + (size_t)r0 * 128 + cg * 8);
    float f0[8];
#pragma unroll
    for (int j = 0; j < 8; ++j) f0[j] = bf2f((unsigned short)v0[j]);
    pacc8(i, b1, b2, b3, f0, a0, a1, a2, a3);
  }
  __shared__ float red[16][4][128];
#pragma unroll
  for (int j = 0; j < 8; ++j) {
    red[slot][0][cg * 8 + j] = a0[j];
    red[slot][1][cg * 8 + j] = a1[j];
    red[slot][2][cg * 8 + j] = a2[j];
    red[slot][3][cg * 8 + j] = a3[j];
  }
  __syncthreads();
#pragma unroll
  for (int rr = 0; rr < 2; ++rr) {
    int idx = t + rr * 256;
    int nd = idx >> 7, col = idx & 127;
    float s = 0.f;
#pragma unroll
    for (int r = 0; r < 16; ++r) s += red[r][nd][col];
    int n = n0 + nd;
    if (n < N) outagg[(size_t)n * 128 + col] = f2bf(s);
  }
}

// ---------------- MFMA fused transform ----------------
__global__ __launch_bounds__(256) void gemm_mfma_kernel(
    const unsigned short* __restrict__ A1, int w1, int k1,
    const unsigned short* __restrict__ A2, int w2, int k2,
    const unsigned short* __restrict__ A3, int w3, int k3,
    const unsigned short* __restrict__ Wt, int Ktot,
    const float* __restrict__ be, const float* __restrict__ br,
    const int* __restrict__ deg, unsigned short* __restrict__ out, int N) {
  int t = threadIdx.x;
  int wave = t >> 6, lane = t & 63;
  int rit = lane & 15, kgrp = lane >> 4;
  int n0 = blockIdx.x * 64;
  int arow = n0 + wave * 16 + rit;
  if (arow >= N) arow = N - 1;
  f32x4 acc[8];
#pragma unroll
  for (int c = 0; c < 8; ++c) acc[c] = (f32x4){0.f, 0.f, 0.f, 0.f};

  const unsigned short* As[3] = {A1, A2, A3};
  const int wds[3] = {w1, w2, w3};
  const int ks[3] = {k1, k2, k3};
  int kbase = 0;
  for (int s = 0; s < 3; ++s) {
    const unsigned short* Arow = As[s] + (size_t)arow * wds[s] + kgrp * 8;
    int K = ks[s];
    for (int kk = 0; kk < K; kk += 32) {
      short8v a = *(const short8v*)(Arow + kk);
      int kg = kbase + kk + kgrp * 8;
#pragma unroll
      for (int c = 0; c < 8; ++c) {
        short8v b = *(const short8v*)(Wt + (size_t)(c * 16 + rit) * Ktot + kg);
        acc[c] = __builtin_amdgcn_mfma_f32_16x16x32_bf16(a, b, acc[c], 0, 0, 0);
      }
    }
    kbase += K;
  }

  __shared__ unsigned short st[64][136];
  float dg[4];
#pragma unroll
  for (int r = 0; r < 4; ++r) {
    int n = n0 + wave * 16 + kgrp * 4 + r;
    dg[r] = (float)deg[n < N ? n : N - 1];
  }
#pragma unroll
  for (int c = 0; c < 8; ++c) {
    int col = c * 16 + rit;
    float bev = be[col], brv = br[col];
#pragma unroll
    for (int r = 0; r < 4; ++r) {
      float v = acc[c][r] + dg[r] * bev + brv;
      st[wave * 16 + kgrp * 4 + r][col] = f2bf(fmaxf(v, 0.f));
    }
  }
  __syncthreads();
#pragma unroll
  for (int it = 0; it < 4; ++it) {
    int idx = t + it * 256;
    int row = idx >> 4, cg = idx & 15;
    int n = n0 + row;
    if (n < N)
      *(short8v*)(out + (size_t)n * 128 + cg * 8) = *(const short8v*)(&st[row][cg * 8]);
  }
}

// ---------------- Graph pooling (batch sorted), bf16 in, fp32 out ----------------
__global__ void pool_kernel(const unsigned short* __restrict__ x, const int* __restrict__ batch,
                            float* __restrict__ out, int N) {
  int n0 = blockIdx.x * 128;
  int c = threadIdx.x;
  if (n0 >= N) return;
  int end = min(n0 + 128, N);
  float acc = 0.f;
  int g = batch[n0];
  for (int n = n0; n < end; ++n) {
    int gn = batch[n];
    if (gn != g) {
      atomicAdd(&out[g * 128 + c], acc);
      acc = 0.f;
      g = gn;
    }
    acc += bf2f(x[(size_t)n * 128 + c]);
  }
  atomicAdd(&out[g * 128 + c], acc);
}

// ---------------- launch ----------------

extern "C" void kernel_launch(void* const* d_in, const int* in_sizes, int n_in,
                              void* d_out, int out_size, void* d_ws, size_t ws_size,
                              hipStream_t stream) {
  const float* x_in       = (const float*)d_in[0];
  const int*   edge_index = (const int*)d_in[1];
  const float* edge_attr  = (const float*)d_in[2];
  const int*   batch      = (const int*)d_in[3];
  const float* We0 = (const float*)d_in[4];
  const float* be0 = (const float*)d_in[5];
  const float* Wr0 = (const float*)d_in[6];
  const float* br0 = (const float*)d_in[7];
  const float* We1 = (const float*)d_in[8];
  const float* be1 = (const float*)d_in[9];
  const float* Wr1 = (const float*)d_in[10];
  const float* br1 = (const float*)d_in[11];
  const float* We2 = (const float*)d_in[12];
  const float* be2 = (const float*)d_in[13];
  const float* Wr2 = (const float*)d_in[14];
  const float* br2 = (const float*)d_in[15];

  float* out = (float*)d_out;

  int N = in_sizes[0] / 64;   // 50000
  int E = in_sizes[1] / 2;    // 1600000
  const int* src = edge_index;
  const int* dst = edge_index + E;

  char* w = (char*)d_ws;
  size_t off = 0;
  auto alloc = [&](size_t bytes) {
    void* p = w + off;
    off += (bytes + 255) & ~(size_t)255;
    return p;
  };
  int* deg   = (int*)alloc((size_t)N * 4);
  int* cnt   = (int*)alloc((size_t)N * 4);
  size_t zero_bytes = off;  // deg + cnt zeroed each call
  int* ptrs  = (int*)alloc((size_t)(N + 1) * 4);
  int* bsum  = (int*)alloc(128 * 4);
  int* boffs = (int*)alloc(128 * 4);
  int2* csr  = (int2*)alloc((size_t)E * 8);
  unsigned short* x_bf   = (unsigned short*)alloc((size_t)N * 64 * 2);
  unsigned short* aggx64 = (unsigned short*)alloc((size_t)N * 64 * 2);
  unsigned short* agge   = (unsigned short*)alloc((size_t)N * 64 * 2);
  unsigned short* aggx   = (unsigned short*)alloc((size_t)N * 128 * 2);
  unsigned short* xb0    = (unsigned short*)alloc((size_t)N * 128 * 2);
  unsigned short* xb1    = (unsigned short*)alloc((size_t)N * 128 * 2);
  unsigned short* Wt0    = (unsigned short*)alloc((size_t)128 * 192 * 2);
  unsigned short* Wt1    = (unsigned short*)alloc((size_t)128 * 320 * 2);
  unsigned short* Wt2    = (unsigned short*)alloc((size_t)128 * 320 * 2);

  (void)hipMemsetAsync(d_ws, 0, zero_bytes, stream);
  (void)hipMemsetAsync(d_out, 0, (size_t)out_size * sizeof(float), stream);

  int eb = (E + 255) / 256;
  int sb = (N + 511) / 512;
  count_deg_kernel<<<eb, 256, 0, stream>>>(dst, deg, E);
  block_sum_kernel<<<sb, 512, 0, stream>>>(deg, bsum, N);
  scan_small_kernel<<<1, 128, 0, stream>>>(bsum, boffs, sb);
  ptrs_kernel<<<sb, 512, 0, stream>>>(deg, boffs, ptrs, N);
  fill_csr_kernel<<<eb, 256, 0, stream>>>(src, dst, ptrs, cnt, csr, E);

  // conversions (independent of CSR)
  f2bf_stream_kernel<<<(N * 64 / 8 + 255) / 256, 256, 0, stream>>>(x_in, x_bf, N * 64);
  {
    int total = 128 * 192 + 2 * 128 * 320;
    pack_all_kernel<<<(total + 255) / 256, 256, 0, stream>>>(We0, Wr0, We1, Wr1, We2, Wr2,
                                                             Wt0, Wt1, Wt2);
  }

  int gb = (N + 63) / 64;
  int ab = (N + 3) / 4;

  // layer-invariant edge aggregate + layer-0 x aggregate
  agg_ea_kernel<<<ab, 256, 0, stream>>>(ptrs, csr, edge_attr, agge, N);
  agg_bf64_kernel<<<ab, 256, 0, stream>>>(ptrs, csr, x_bf, aggx64, N);

  // Layer 0: K-order (aggx64:We0[0:64], agge:We0[64:128], x:Wr0)
  gemm_mfma_kernel<<<gb, 256, 0, stream>>>(aggx64, 64, 64, agge, 64, 64, x_bf, 64, 64,
                                           Wt0, 192, be0, br0, deg, xb0, N);
  // Layer 1
  agg_bf128_kernel<<<ab, 256, 0, stream>>>(ptrs, csr, xb0, aggx, N);
  gemm_mfma_kernel<<<gb, 256, 0, stream>>>(aggx, 128, 128, agge, 64, 64, xb0, 128, 128,
                                           Wt1, 320, be1, br1, deg, xb1, N);
  // Layer 2
  agg_bf128_kernel<<<ab, 256, 0, stream>>>(ptrs, csr, xb1, aggx, N);
  gemm_mfma_kernel<<<gb, 256, 0, stream>>>(aggx, 128, 128, agge, 64, 64, xb1, 128, 128,
                                           Wt2, 320, be2, br2, deg, xb0, N);
  // Readout
  pool_kernel<<<(N + 127) / 128, 128, 0, stream>>>(xb0, batch, out, N);
}

// Round 7
// 539.862 us; speedup vs baseline: 2.1790x; 2.1790x over previous
//
#include <hip/hip_runtime.h>
#include <hip/hip_bf16.h>
#include <cstdint>

typedef __attribute__((ext_vector_type(8))) short short8v;
typedef __attribute__((ext_vector_type(4))) short short4v;
typedef __attribute__((ext_vector_type(4))) float f32x4;

__device__ __forceinline__ float4 add4(float4 a, float4 b) {
  return make_float4(a.x + b.x, a.y + b.y, a.z + b.z, a.w + b.w);
}
__device__ __forceinline__ float bf2f(unsigned short u) {
  union { unsigned int i; float f; } v; v.i = ((unsigned int)u) << 16; return v.f;
}
__device__ __forceinline__ unsigned short f2bf(float f) {
  union { float f; unsigned int i; } v; v.f = f;
  unsigned int r = v.i + 0x7fff + ((v.i >> 16) & 1);
  return (unsigned short)(r >> 16);
}
__device__ __forceinline__ float4 shflx4(float4 a, int m) {
  return make_float4(__shfl_xor(a.x, m, 64), __shfl_xor(a.y, m, 64),
                     __shfl_xor(a.z, m, 64), __shfl_xor(a.w, m, 64));
}
// accumulate 8 bf16 into two float4s (all named registers)
__device__ __forceinline__ void acc8(float4& lo, float4& hi, short8v v) {
  lo.x += bf2f((unsigned short)v[0]); lo.y += bf2f((unsigned short)v[1]);
  lo.z += bf2f((unsigned short)v[2]); lo.w += bf2f((unsigned short)v[3]);
  hi.x += bf2f((unsigned short)v[4]); hi.y += bf2f((unsigned short)v[5]);
  hi.z += bf2f((unsigned short)v[6]); hi.w += bf2f((unsigned short)v[7]);
}

// ---------------- CSR build ----------------

__global__ void count_deg_kernel(const int* __restrict__ dst, int* __restrict__ deg, int E) {
  int i = blockIdx.x * blockDim.x + threadIdx.x;
  if (i < E) atomicAdd(&deg[dst[i]], 1);
}

__global__ void block_sum_kernel(const int* __restrict__ deg, int* __restrict__ bsum, int N) {
  int t = threadIdx.x;
  int i = blockIdx.x * 512 + t;
  int v = (i < N) ? deg[i] : 0;
#pragma unroll
  for (int off = 32; off > 0; off >>= 1) v += __shfl_down(v, off, 64);
  __shared__ int ws[8];
  int lane = t & 63, wid = t >> 6;
  if (lane == 0) ws[wid] = v;
  __syncthreads();
  if (t == 0) {
    int s = 0;
#pragma unroll
    for (int j = 0; j < 8; ++j) s += ws[j];
    bsum[blockIdx.x] = s;
  }
}

__global__ void scan_small_kernel(const int* __restrict__ bsum, int* __restrict__ boffs, int B) {
  int t = threadIdx.x;
  int lane = t & 63, wid = t >> 6;
  int v = (t < B) ? bsum[t] : 0;
  int incl = v;
#pragma unroll
  for (int off = 1; off < 64; off <<= 1) {
    int u = __shfl_up(incl, off, 64);
    if (lane >= off) incl += u;
  }
  __shared__ int ws[2];
  if (lane == 63) ws[wid] = incl;
  __syncthreads();
  int base = (wid == 1) ? ws[0] : 0;
  if (t < B) boffs[t] = base + incl - v;
}

__global__ void ptrs_kernel(const int* __restrict__ deg, const int* __restrict__ boffs,
                            int* __restrict__ ptrs, int N) {
  int t = threadIdx.x;
  int i = blockIdx.x * 512 + t;
  int lane = t & 63, wid = t >> 6;
  int v = (i < N) ? deg[i] : 0;
  int incl = v;
#pragma unroll
  for (int off = 1; off < 64; off <<= 1) {
    int u = __shfl_up(incl, off, 64);
    if (lane >= off) incl += u;
  }
  __shared__ int ws[8];
  if (lane == 63) ws[wid] = incl;
  __syncthreads();
  if (t == 0) {
    int s = 0;
#pragma unroll
    for (int j = 0; j < 8; ++j) { int tmp = ws[j]; ws[j] = s; s += tmp; }
  }
  __syncthreads();
  if (i < N) ptrs[i + 1] = boffs[blockIdx.x] + ws[wid] + incl;
  if (i == 0 && blockIdx.x == 0) ptrs[0] = 0;
}

__global__ void fill_csr_kernel(const int* __restrict__ src, const int* __restrict__ dst,
                                const int* __restrict__ ptrs, int* __restrict__ cnt,
                                int2* __restrict__ csr, int E) {
  int i = blockIdx.x * blockDim.x + threadIdx.x;
  if (i < E) {
    int d = dst[i];
    int pos = ptrs[d] + atomicAdd(&cnt[d], 1);
    csr[pos] = make_int2(src[i], i);
  }
}

// ---------------- conversions ----------------

__global__ void f2bf_stream_kernel(const float* __restrict__ in, unsigned short* __restrict__ out, int n) {
  int i = (blockIdx.x * blockDim.x + threadIdx.x) * 8;
  if (i < n) {
    float4 v0 = *(const float4*)(in + i);
    float4 v1 = *(const float4*)(in + i + 4);
    short8v o;
    o[0] = (short)f2bf(v0.x); o[1] = (short)f2bf(v0.y);
    o[2] = (short)f2bf(v0.z); o[3] = (short)f2bf(v0.w);
    o[4] = (short)f2bf(v1.x); o[5] = (short)f2bf(v1.y);
    o[6] = (short)f2bf(v1.z); o[7] = (short)f2bf(v1.w);
    *(short8v*)(out + i) = o;
  }
}

// pack all three layers' weights: Wt[c][k] = (k<rowsE ? We[k][c] : Wr[k-rowsE][c]) bf16
__global__ void pack_all_kernel(const float* __restrict__ We0, const float* __restrict__ Wr0,
                                const float* __restrict__ We1, const float* __restrict__ Wr1,
                                const float* __restrict__ We2, const float* __restrict__ Wr2,
                                unsigned short* __restrict__ Wt0, unsigned short* __restrict__ Wt1,
                                unsigned short* __restrict__ Wt2) {
  int idx = blockIdx.x * blockDim.x + threadIdx.x;
  const float* We; const float* Wr; unsigned short* Wt;
  int rowsE, Ktot, local;
  if (idx < 128 * 192) {
    We = We0; Wr = Wr0; Wt = Wt0; rowsE = 128; Ktot = 192; local = idx;
  } else if (idx < 128 * 192 + 128 * 320) {
    We = We1; Wr = Wr1; Wt = Wt1; rowsE = 192; Ktot = 320; local = idx - 128 * 192;
  } else if (idx < 128 * 192 + 2 * 128 * 320) {
    We = We2; Wr = Wr2; Wt = Wt2; rowsE = 192; Ktot = 320; local = idx - 128 * 192 - 128 * 320;
  } else {
    return;
  }
  int c = local / Ktot, k = local % Ktot;
  float v = (k < rowsE) ? We[(size_t)k * 128 + c] : Wr[(size_t)(k - rowsE) * 128 + c];
  Wt[local] = f2bf(v);
}

// ---------------- Aggregation: one wave per node, zero LDS ----------------

// edge_attr aggregate: fp32 rows of 64 (256B); 4 slots x 16 lanes; unroll 2.
__global__ __launch_bounds__(256) void agg_ea_kernel(
    const int* __restrict__ ptrs, const int2* __restrict__ csr,
    const float* __restrict__ ea, unsigned short* __restrict__ agge, int N) {
  int t = threadIdx.x;
  int n = blockIdx.x * 4 + (t >> 6);
  if (n >= N) return;
  int lane = t & 63;
  int slot = lane >> 4, cg = lane & 15;
  int s = ptrs[n], e = ptrs[n + 1];
  float4 a0 = make_float4(0, 0, 0, 0), a1 = make_float4(0, 0, 0, 0);
  int i = s + slot;
  for (; i + 4 < e; i += 8) {
    int e0 = csr[i].y, e1 = csr[i + 4].y;
    a0 = add4(a0, *((const float4*)(ea + (size_t)e0 * 64) + cg));
    a1 = add4(a1, *((const float4*)(ea + (size_t)e1 * 64) + cg));
  }
  if (i < e) a0 = add4(a0, *((const float4*)(ea + (size_t)csr[i].y * 64) + cg));
  a0 = add4(a0, a1);
  a0 = add4(a0, shflx4(a0, 16));
  a0 = add4(a0, shflx4(a0, 32));
  if (slot == 0) {
    short4v o;
    o[0] = (short)f2bf(a0.x); o[1] = (short)f2bf(a0.y);
    o[2] = (short)f2bf(a0.z); o[3] = (short)f2bf(a0.w);
    *(short4v*)(agge + (size_t)n * 64 + cg * 4) = o;
  }
}

// bf16 rows of 64 (128B); 8 slots x 8 lanes; unroll 2.
__global__ __launch_bounds__(256) void agg_bf64_kernel(
    const int* __restrict__ ptrs, const int2* __restrict__ csr,
    const unsigned short* __restrict__ xb, unsigned short* __restrict__ outagg, int N) {
  int t = threadIdx.x;
  int n = blockIdx.x * 4 + (t >> 6);
  if (n >= N) return;
  int lane = t & 63;
  int slot = lane >> 3, cg = lane & 7;
  int s = ptrs[n], e = ptrs[n + 1];
  float4 lo0 = make_float4(0, 0, 0, 0), hi0 = make_float4(0, 0, 0, 0);
  float4 lo1 = make_float4(0, 0, 0, 0), hi1 = make_float4(0, 0, 0, 0);
  int i = s + slot;
  for (; i + 8 < e; i += 16) {
    acc8(lo0, hi0, *(const short8v*)(xb + (size_t)csr[i].x * 64 + cg * 8));
    acc8(lo1, hi1, *(const short8v*)(xb + (size_t)csr[i + 8].x * 64 + cg * 8));
  }
  if (i < e) acc8(lo0, hi0, *(const short8v*)(xb + (size_t)csr[i].x * 64 + cg * 8));
  lo0 = add4(lo0, lo1); hi0 = add4(hi0, hi1);
  lo0 = add4(lo0, shflx4(lo0, 8));  hi0 = add4(hi0, shflx4(hi0, 8));
  lo0 = add4(lo0, shflx4(lo0, 16)); hi0 = add4(hi0, shflx4(hi0, 16));
  lo0 = add4(lo0, shflx4(lo0, 32)); hi0 = add4(hi0, shflx4(hi0, 32));
  if (slot == 0) {
    short8v o;
    o[0] = (short)f2bf(lo0.x); o[1] = (short)f2bf(lo0.y);
    o[2] = (short)f2bf(lo0.z); o[3] = (short)f2bf(lo0.w);
    o[4] = (short)f2bf(hi0.x); o[5] = (short)f2bf(hi0.y);
    o[6] = (short)f2bf(hi0.z); o[7] = (short)f2bf(hi0.w);
    *(short8v*)(outagg + (size_t)n * 64 + cg * 8) = o;
  }
}

// bf16 rows of 128 (256B); 4 slots x 16 lanes; unroll 2.
__global__ __launch_bounds__(256) void agg_bf128_kernel(
    const int* __restrict__ ptrs, const int2* __restrict__ csr,
    const unsigned short* __restrict__ xb, unsigned short* __restrict__ outagg, int N) {
  int t = threadIdx.x;
  int n = blockIdx.x * 4 + (t >> 6);
  if (n >= N) return;
  int lane = t & 63;
  int slot = lane >> 4, cg = lane & 15;
  int s = ptrs[n], e = ptrs[n + 1];
  float4 lo0 = make_float4(0, 0, 0, 0), hi0 = make_float4(0, 0, 0, 0);
  float4 lo1 = make_float4(0, 0, 0, 0), hi1 = make_float4(0, 0, 0, 0);
  int i = s + slot;
  for (; i + 4 < e; i += 8) {
    acc8(lo0, hi0, *(const short8v*)(xb + (size_t)csr[i].x * 128 + cg * 8));
    acc8(lo1, hi1, *(const short8v*)(xb + (size_t)csr[i + 4].x * 128 + cg * 8));
  }
  if (i < e) acc8(lo0, hi0, *(const short8v*)(xb + (size_t)csr[i].x * 128 + cg * 8));
  lo0 = add4(lo0, lo1); hi0 = add4(hi0, hi1);
  lo0 = add4(lo0, shflx4(lo0, 16)); hi0 = add4(hi0, shflx4(hi0, 16));
  lo0 = add4(lo0, shflx4(lo0, 32)); hi0 = add4(hi0, shflx4(hi0, 32));
  if (slot == 0) {
    short8v o;
    o[0] = (short)f2bf(lo0.x); o[1] = (short)f2bf(lo0.y);
    o[2] = (short)f2bf(lo0.z); o[3] = (short)f2bf(lo0.w);
    o[4] = (short)f2bf(hi0.x); o[5] = (short)f2bf(hi0.y);
    o[6] = (short)f2bf(hi0.z); o[7] = (short)f2bf(hi0.w);
    *(short8v*)(outagg + (size_t)n * 128 + cg * 8) = o;
  }
}

// ---------------- MFMA fused transform ----------------
__global__ __launch_bounds__(256) void gemm_mfma_kernel(
    const unsigned short* __restrict__ A1, int w1, int k1,
    const unsigned short* __restrict__ A2, int w2, int k2,
    const unsigned short* __restrict__ A3, int w3, int k3,
    const unsigned short* __restrict__ Wt, int Ktot,
    const float* __restrict__ be, const float* __restrict__ br,
    const int* __restrict__ deg, unsigned short* __restrict__ out, int N) {
  int t = threadIdx.x;
  int wave = t >> 6, lane = t & 63;
  int rit = lane & 15, kgrp = lane >> 4;
  int n0 = blockIdx.x * 64;
  int arow = n0 + wave * 16 + rit;
  if (arow >= N) arow = N - 1;
  f32x4 acc[8];
#pragma unroll
  for (int c = 0; c < 8; ++c) acc[c] = (f32x4){0.f, 0.f, 0.f, 0.f};

  const unsigned short* As[3] = {A1, A2, A3};
  const int wds[3] = {w1, w2, w3};
  const int ks[3] = {k1, k2, k3};
  int kbase = 0;
  for (int s = 0; s < 3; ++s) {
    const unsigned short* Arow = As[s] + (size_t)arow * wds[s] + kgrp * 8;
    int K = ks[s];
    for (int kk = 0; kk < K; kk += 32) {
      short8v a = *(const short8v*)(Arow + kk);
      int kg = kbase + kk + kgrp * 8;
#pragma unroll
      for (int c = 0; c < 8; ++c) {
        short8v b = *(const short8v*)(Wt + (size_t)(c * 16 + rit) * Ktot + kg);
        acc[c] = __builtin_amdgcn_mfma_f32_16x16x32_bf16(a, b, acc[c], 0, 0, 0);
      }
    }
    kbase += K;
  }

  __shared__ unsigned short st[64][136];
  float dg[4];
#pragma unroll
  for (int r = 0; r < 4; ++r) {
    int n = n0 + wave * 16 + kgrp * 4 + r;
    dg[r] = (float)deg[n < N ? n : N - 1];
  }
#pragma unroll
  for (int c = 0; c < 8; ++c) {
    int col = c * 16 + rit;
    float bev = be[col], brv = br[col];
#pragma unroll
    for (int r = 0; r < 4; ++r) {
      float v = acc[c][r] + dg[r] * bev + brv;
      st[wave * 16 + kgrp * 4 + r][col] = f2bf(fmaxf(v, 0.f));
    }
  }
  __syncthreads();
#pragma unroll
  for (int it = 0; it < 4; ++it) {
    int idx = t + it * 256;
    int row = idx >> 4, cg = idx & 15;
    int n = n0 + row;
    if (n < N)
      *(short8v*)(out + (size_t)n * 128 + cg * 8) = *(const short8v*)(&st[row][cg * 8]);
  }
}

// ---------------- Graph pooling (batch sorted), bf16 in, fp32 out ----------------
__global__ void pool_kernel(const unsigned short* __restrict__ x, const int* __restrict__ batch,
                            float* __restrict__ out, int N) {
  int n0 = blockIdx.x * 128;
  int c = threadIdx.x;
  if (n0 >= N) return;
  int end = min(n0 + 128, N);
  float acc = 0.f;
  int g = batch[n0];
  for (int n = n0; n < end; ++n) {
    int gn = batch[n];
    if (gn != g) {
      atomicAdd(&out[g * 128 + c], acc);
      acc = 0.f;
      g = gn;
    }
    acc += bf2f(x[(size_t)n * 128 + c]);
  }
  atomicAdd(&out[g * 128 + c], acc);
}

// ---------------- launch ----------------

extern "C" void kernel_launch(void* const* d_in, const int* in_sizes, int n_in,
                              void* d_out, int out_size, void* d_ws, size_t ws_size,
                              hipStream_t stream) {
  const float* x_in       = (const float*)d_in[0];
  const int*   edge_index = (const int*)d_in[1];
  const float* edge_attr  = (const float*)d_in[2];
  const int*   batch      = (const int*)d_in[3];
  const float* We0 = (const float*)d_in[4];
  const float* be0 = (const float*)d_in[5];
  const float* Wr0 = (const float*)d_in[6];
  const float* br0 = (const float*)d_in[7];
  const float* We1 = (const float*)d_in[8];
  const float* be1 = (const float*)d_in[9];
  const float* Wr1 = (const float*)d_in[10];
  const float* br1 = (const float*)d_in[11];
  const float* We2 = (const float*)d_in[12];
  const float* be2 = (const float*)d_in[13];
  const float* Wr2 = (const float*)d_in[14];
  const float* br2 = (const float*)d_in[15];

  float* out = (float*)d_out;

  int N = in_sizes[0] / 64;   // 50000
  int E = in_sizes[1] / 2;    // 1600000
  const int* src = edge_index;
  const int* dst = edge_index + E;

  char* w = (char*)d_ws;
  size_t off = 0;
  auto alloc = [&](size_t bytes) {
    void* p = w + off;
    off += (bytes + 255) & ~(size_t)255;
    return p;
  };
  int* deg   = (int*)alloc((size_t)N * 4);
  int* cnt   = (int*)alloc((size_t)N * 4);
  size_t zero_bytes = off;  // deg + cnt zeroed each call
  int* ptrs  = (int*)alloc((size_t)(N + 1) * 4);
  int* bsum  = (int*)alloc(128 * 4);
  int* boffs = (int*)alloc(128 * 4);
  int2* csr  = (int2*)alloc((size_t)E * 8);
  unsigned short* x_bf   = (unsigned short*)alloc((size_t)N * 64 * 2);
  unsigned short* aggx64 = (unsigned short*)alloc((size_t)N * 64 * 2);
  unsigned short* agge   = (unsigned short*)alloc((size_t)N * 64 * 2);
  unsigned short* aggx   = (unsigned short*)alloc((size_t)N * 128 * 2);
  unsigned short* xb0    = (unsigned short*)alloc((size_t)N * 128 * 2);
  unsigned short* xb1    = (unsigned short*)alloc((size_t)N * 128 * 2);
  unsigned short* Wt0    = (unsigned short*)alloc((size_t)128 * 192 * 2);
  unsigned short* Wt1    = (unsigned short*)alloc((size_t)128 * 320 * 2);
  unsigned short* Wt2    = (unsigned short*)alloc((size_t)128 * 320 * 2);

  (void)hipMemsetAsync(d_ws, 0, zero_bytes, stream);
  (void)hipMemsetAsync(d_out, 0, (size_t)out_size * sizeof(float), stream);

  int eb = (E + 255) / 256;
  int sb = (N + 511) / 512;
  count_deg_kernel<<<eb, 256, 0, stream>>>(dst, deg, E);
  block_sum_kernel<<<sb, 512, 0, stream>>>(deg, bsum, N);
  scan_small_kernel<<<1, 128, 0, stream>>>(bsum, boffs, sb);
  ptrs_kernel<<<sb, 512, 0, stream>>>(deg, boffs, ptrs, N);
  fill_csr_kernel<<<eb, 256, 0, stream>>>(src, dst, ptrs, cnt, csr, E);

  // conversions (independent of CSR)
  f2bf_stream_kernel<<<(N * 64 / 8 + 255) / 256, 256, 0, stream>>>(x_in, x_bf, N * 64);
  {
    int total = 128 * 192 + 2 * 128 * 320;
    pack_all_kernel<<<(total + 255) / 256, 256, 0, stream>>>(We0, Wr0, We1, Wr1, We2, Wr2,
                                                             Wt0, Wt1, Wt2);
  }

  int gb = (N + 63) / 64;
  int ab = (N + 3) / 4;

  // layer-invariant edge aggregate + layer-0 x aggregate
  agg_ea_kernel<<<ab, 256, 0, stream>>>(ptrs, csr, edge_attr, agge, N);
  agg_bf64_kernel<<<ab, 256, 0, stream>>>(ptrs, csr, x_bf, aggx64, N);

  // Layer 0: K-order (aggx64:We0[0:64], agge:We0[64:128], x:Wr0)
  gemm_mfma_kernel<<<gb, 256, 0, stream>>>(aggx64, 64, 64, agge, 64, 64, x_bf, 64, 64,
                                           Wt0, 192, be0, br0, deg, xb0, N);
  // Layer 1
  agg_bf128_kernel<<<ab, 256, 0, stream>>>(ptrs, csr, xb0, aggx, N);
  gemm_mfma_kernel<<<gb, 256, 0, stream>>>(aggx, 128, 128, agge, 64, 64, xb0, 128, 128,
                                           Wt1, 320, be1, br1, deg, xb1, N);
  // Layer 2
  agg_bf128_kernel<<<ab, 256, 0, stream>>>(ptrs, csr, xb1, aggx, N);
  gemm_mfma_kernel<<<gb, 256, 0, stream>>>(aggx, 128, 128, agge, 64, 64, xb1, 128, 128,
                                           Wt2, 320, be2, br2, deg, xb0, N);
  // Readout
  pool_kernel<<<(N + 127) / 128, 128, 0, stream>>>(xb0, batch, out, N);
}

// Round 8
// 491.101 us; speedup vs baseline: 2.3954x; 1.0993x over previous
//
#include <hip/hip_runtime.h>
#include <hip/hip_bf16.h>
#include <cstdint>

typedef __attribute__((ext_vector_type(8))) short short8v;
typedef __attribute__((ext_vector_type(4))) short short4v;
typedef __attribute__((ext_vector_type(4))) float f32x4;

__device__ __forceinline__ float4 add4(float4 a, float4 b) {
  return make_float4(a.x + b.x, a.y + b.y, a.z + b.z, a.w + b.w);
}
__device__ __forceinline__ float bf2f(unsigned short u) {
  union { unsigned int i; float f; } v; v.i = ((unsigned int)u) << 16; return v.f;
}
__device__ __forceinline__ unsigned short f2bf(float f) {
  union { float f; unsigned int i; } v; v.f = f;
  unsigned int r = v.i + 0x7fff + ((v.i >> 16) & 1);
  return (unsigned short)(r >> 16);
}
__device__ __forceinline__ float4 shflx4(float4 a, int m) {
  return make_float4(__shfl_xor(a.x, m, 64), __shfl_xor(a.y, m, 64),
                     __shfl_xor(a.z, m, 64), __shfl_xor(a.w, m, 64));
}
__device__ __forceinline__ void acc8(float4& lo, float4& hi, short8v v) {
  lo.x += bf2f((unsigned short)v[0]); lo.y += bf2f((unsigned short)v[1]);
  lo.z += bf2f((unsigned short)v[2]); lo.w += bf2f((unsigned short)v[3]);
  hi.x += bf2f((unsigned short)v[4]); hi.y += bf2f((unsigned short)v[5]);
  hi.z += bf2f((unsigned short)v[6]); hi.w += bf2f((unsigned short)v[7]);
}

// ---------------- CSR build ----------------

__global__ void count_deg_kernel(const int* __restrict__ dst, int* __restrict__ deg, int E) {
  int i = blockIdx.x * blockDim.x + threadIdx.x;
  if (i < E) atomicAdd(&deg[dst[i]], 1);
}

__global__ void block_sum_kernel(const int* __restrict__ deg, int* __restrict__ bsum, int N) {
  int t = threadIdx.x;
  int i = blockIdx.x * 512 + t;
  int v = (i < N) ? deg[i] : 0;
#pragma unroll
  for (int off = 32; off > 0; off >>= 1) v += __shfl_down(v, off, 64);
  __shared__ int ws[8];
  int lane = t & 63, wid = t >> 6;
  if (lane == 0) ws[wid] = v;
  __syncthreads();
  if (t == 0) {
    int s = 0;
#pragma unroll
    for (int j = 0; j < 8; ++j) s += ws[j];
    bsum[blockIdx.x] = s;
  }
}

__global__ void scan_small_kernel(const int* __restrict__ bsum, int* __restrict__ boffs, int B) {
  int t = threadIdx.x;
  int lane = t & 63, wid = t >> 6;
  int v = (t < B) ? bsum[t] : 0;
  int incl = v;
#pragma unroll
  for (int off = 1; off < 64; off <<= 1) {
    int u = __shfl_up(incl, off, 64);
    if (lane >= off) incl += u;
  }
  __shared__ int ws[2];
  if (lane == 63) ws[wid] = incl;
  __syncthreads();
  int base = (wid == 1) ? ws[0] : 0;
  if (t < B) boffs[t] = base + incl - v;
}

__global__ void ptrs_kernel(const int* __restrict__ deg, const int* __restrict__ boffs,
                            int* __restrict__ ptrs, int N) {
  int t = threadIdx.x;
  int i = blockIdx.x * 512 + t;
  int lane = t & 63, wid = t >> 6;
  int v = (i < N) ? deg[i] : 0;
  int incl = v;
#pragma unroll
  for (int off = 1; off < 64; off <<= 1) {
    int u = __shfl_up(incl, off, 64);
    if (lane >= off) incl += u;
  }
  __shared__ int ws[8];
  if (lane == 63) ws[wid] = incl;
  __syncthreads();
  if (t == 0) {
    int s = 0;
#pragma unroll
    for (int j = 0; j < 8; ++j) { int tmp = ws[j]; ws[j] = s; s += tmp; }
  }
  __syncthreads();
  if (i < N) ptrs[i + 1] = boffs[blockIdx.x] + ws[wid] + incl;
  if (i == 0 && blockIdx.x == 0) ptrs[0] = 0;
}

__global__ void fill_csr_kernel(const int* __restrict__ src, const int* __restrict__ dst,
                                const int* __restrict__ ptrs, int* __restrict__ cnt,
                                int2* __restrict__ csr, int E) {
  int i = blockIdx.x * blockDim.x + threadIdx.x;
  if (i < E) {
    int d = dst[i];
    int pos = ptrs[d] + atomicAdd(&cnt[d], 1);
    csr[pos] = make_int2(src[i], i);
  }
}

// ---------------- conversions ----------------

__global__ void f2bf_stream_kernel(const float* __restrict__ in, unsigned short* __restrict__ out, int n) {
  int i = (blockIdx.x * blockDim.x + threadIdx.x) * 8;
  if (i < n) {
    float4 v0 = *(const float4*)(in + i);
    float4 v1 = *(const float4*)(in + i + 4);
    short8v o;
    o[0] = (short)f2bf(v0.x); o[1] = (short)f2bf(v0.y);
    o[2] = (short)f2bf(v0.z); o[3] = (short)f2bf(v0.w);
    o[4] = (short)f2bf(v1.x); o[5] = (short)f2bf(v1.y);
    o[6] = (short)f2bf(v1.z); o[7] = (short)f2bf(v1.w);
    *(short8v*)(out + i) = o;
  }
}

// pack all three layers' weights: Wt[c][k] = (k<rowsE ? We[k][c] : Wr[k-rowsE][c]) bf16
__global__ void pack_all_kernel(const float* __restrict__ We0, const float* __restrict__ Wr0,
                                const float* __restrict__ We1, const float* __restrict__ Wr1,
                                const float* __restrict__ We2, const float* __restrict__ Wr2,
                                unsigned short* __restrict__ Wt0, unsigned short* __restrict__ Wt1,
                                unsigned short* __restrict__ Wt2) {
  int idx = blockIdx.x * blockDim.x + threadIdx.x;
  const float* We; const float* Wr; unsigned short* Wt;
  int rowsE, Ktot, local;
  if (idx < 128 * 192) {
    We = We0; Wr = Wr0; Wt = Wt0; rowsE = 128; Ktot = 192; local = idx;
  } else if (idx < 128 * 192 + 128 * 320) {
    We = We1; Wr = Wr1; Wt = Wt1; rowsE = 192; Ktot = 320; local = idx - 128 * 192;
  } else if (idx < 128 * 192 + 2 * 128 * 320) {
    We = We2; Wr = Wr2; Wt = Wt2; rowsE = 192; Ktot = 320; local = idx - 128 * 192 - 128 * 320;
  } else {
    return;
  }
  int c = local / Ktot, k = local % Ktot;
  float v = (k < rowsE) ? We[(size_t)k * 128 + c] : Wr[(size_t)(k - rowsE) * 128 + c];
  Wt[local] = f2bf(v);
}

// ---------------- Layer-0 fused aggregation: ea (HBM) + x (L2) in one CSR pass ----------------
// One wave per node. ea: 4 slots x 16 lanes (float4); x: 8 slots x 8 lanes (short8).
// Both streams advance 8 edges per loop iteration.
__global__ __launch_bounds__(256) void agg0_kernel(
    const int* __restrict__ ptrs, const int2* __restrict__ csr,
    const float* __restrict__ ea, const unsigned short* __restrict__ xb,
    unsigned short* __restrict__ agge, unsigned short* __restrict__ aggx64, int N) {
  int t = threadIdx.x;
  int n = blockIdx.x * 4 + (t >> 6);
  if (n >= N) return;
  int lane = t & 63;
  int slot_a = lane >> 4, cg_a = lane & 15;  // ea role
  int slot_b = lane >> 3, cg_b = lane & 7;   // x role
  int s = ptrs[n], e = ptrs[n + 1];
  float4 z = make_float4(0, 0, 0, 0);
  float4 a0 = z, a1 = z;          // ea accumulators (2 slots' worth per lane)
  float4 xlo = z, xhi = z;        // x accumulators
  int i = s;
  for (; i + 8 <= e; i += 8) {
    int e0 = csr[i + slot_a].y;
    int e1 = csr[i + 4 + slot_a].y;
    int r0 = csr[i + slot_b].x;
    a0 = add4(a0, *((const float4*)(ea + (size_t)e0 * 64) + cg_a));
    a1 = add4(a1, *((const float4*)(ea + (size_t)e1 * 64) + cg_a));
    acc8(xlo, xhi, *(const short8v*)(xb + (size_t)r0 * 64 + cg_b * 8));
  }
  // tail (< 8 edges)
  if (i + slot_a < e)
    a0 = add4(a0, *((const float4*)(ea + (size_t)csr[i + slot_a].y * 64) + cg_a));
  if (i + 4 + slot_a < e)
    a1 = add4(a1, *((const float4*)(ea + (size_t)csr[i + 4 + slot_a].y * 64) + cg_a));
  if (i + slot_b < e)
    acc8(xlo, xhi, *(const short8v*)(xb + (size_t)csr[i + slot_b].x * 64 + cg_b * 8));

  // ea reduce across 4 slots (lane bits 4,5)
  a0 = add4(a0, a1);
  a0 = add4(a0, shflx4(a0, 16));
  a0 = add4(a0, shflx4(a0, 32));
  if (slot_a == 0) {
    short4v o;
    o[0] = (short)f2bf(a0.x); o[1] = (short)f2bf(a0.y);
    o[2] = (short)f2bf(a0.z); o[3] = (short)f2bf(a0.w);
    *(short4v*)(agge + (size_t)n * 64 + cg_a * 4) = o;
  }
  // x reduce across 8 slots (lane bits 3,4,5)
  xlo = add4(xlo, shflx4(xlo, 8));  xhi = add4(xhi, shflx4(xhi, 8));
  xlo = add4(xlo, shflx4(xlo, 16)); xhi = add4(xhi, shflx4(xhi, 16));
  xlo = add4(xlo, shflx4(xlo, 32)); xhi = add4(xhi, shflx4(xhi, 32));
  if (slot_b == 0) {
    short8v o;
    o[0] = (short)f2bf(xlo.x); o[1] = (short)f2bf(xlo.y);
    o[2] = (short)f2bf(xlo.z); o[3] = (short)f2bf(xlo.w);
    o[4] = (short)f2bf(xhi.x); o[5] = (short)f2bf(xhi.y);
    o[6] = (short)f2bf(xhi.z); o[7] = (short)f2bf(xhi.w);
    *(short8v*)(aggx64 + (size_t)n * 64 + cg_b * 8) = o;
  }
}

// bf16 rows of 128 (256B); one wave per node; 4 slots x 16 lanes; unroll 2.
__global__ __launch_bounds__(256) void agg_bf128_kernel(
    const int* __restrict__ ptrs, const int2* __restrict__ csr,
    const unsigned short* __restrict__ xb, unsigned short* __restrict__ outagg, int N) {
  int t = threadIdx.x;
  int n = blockIdx.x * 4 + (t >> 6);
  if (n >= N) return;
  int lane = t & 63;
  int slot = lane >> 4, cg = lane & 15;
  int s = ptrs[n], e = ptrs[n + 1];
  float4 lo0 = make_float4(0, 0, 0, 0), hi0 = make_float4(0, 0, 0, 0);
  float4 lo1 = make_float4(0, 0, 0, 0), hi1 = make_float4(0, 0, 0, 0);
  int i = s + slot;
  for (; i + 4 < e; i += 8) {
    acc8(lo0, hi0, *(const short8v*)(xb + (size_t)csr[i].x * 128 + cg * 8));
    acc8(lo1, hi1, *(const short8v*)(xb + (size_t)csr[i + 4].x * 128 + cg * 8));
  }
  if (i < e) acc8(lo0, hi0, *(const short8v*)(xb + (size_t)csr[i].x * 128 + cg * 8));
  lo0 = add4(lo0, lo1); hi0 = add4(hi0, hi1);
  lo0 = add4(lo0, shflx4(lo0, 16)); hi0 = add4(hi0, shflx4(hi0, 16));
  lo0 = add4(lo0, shflx4(lo0, 32)); hi0 = add4(hi0, shflx4(hi0, 32));
  if (slot == 0) {
    short8v o;
    o[0] = (short)f2bf(lo0.x); o[1] = (short)f2bf(lo0.y);
    o[2] = (short)f2bf(lo0.z); o[3] = (short)f2bf(lo0.w);
    o[4] = (short)f2bf(hi0.x); o[5] = (short)f2bf(hi0.y);
    o[6] = (short)f2bf(hi0.z); o[7] = (short)f2bf(hi0.w);
    *(short8v*)(outagg + (size_t)n * 128 + cg * 8) = o;
  }
}

// ---------------- MFMA fused transform (optionally with fused graph pooling) ----------------
template <int POOL>
__global__ __launch_bounds__(256) void gemm_mfma_kernel(
    const unsigned short* __restrict__ A1, int w1, int k1,
    const unsigned short* __restrict__ A2, int w2, int k2,
    const unsigned short* __restrict__ A3, int w3, int k3,
    const unsigned short* __restrict__ Wt, int Ktot,
    const float* __restrict__ be, const float* __restrict__ br,
    const int* __restrict__ deg, const int* __restrict__ batch,
    unsigned short* __restrict__ out, float* __restrict__ pout, int N) {
  int t = threadIdx.x;
  int wave = t >> 6, lane = t & 63;
  int rit = lane & 15, kgrp = lane >> 4;
  int n0 = blockIdx.x * 64;
  int arow = n0 + wave * 16 + rit;
  if (arow >= N) arow = N - 1;
  f32x4 acc[8];
#pragma unroll
  for (int c = 0; c < 8; ++c) acc[c] = (f32x4){0.f, 0.f, 0.f, 0.f};

  const unsigned short* As[3] = {A1, A2, A3};
  const int wds[3] = {w1, w2, w3};
  const int ks[3] = {k1, k2, k3};
  int kbase = 0;
  for (int s = 0; s < 3; ++s) {
    const unsigned short* Arow = As[s] + (size_t)arow * wds[s] + kgrp * 8;
    int K = ks[s];
    for (int kk = 0; kk < K; kk += 32) {
      short8v a = *(const short8v*)(Arow + kk);
      int kg = kbase + kk + kgrp * 8;
#pragma unroll
      for (int c = 0; c < 8; ++c) {
        short8v b = *(const short8v*)(Wt + (size_t)(c * 16 + rit) * Ktot + kg);
        acc[c] = __builtin_amdgcn_mfma_f32_16x16x32_bf16(a, b, acc[c], 0, 0, 0);
      }
    }
    kbase += K;
  }

  __shared__ unsigned short st[64][136];
  __shared__ int bsh[64];
  float dg[4];
#pragma unroll
  for (int r = 0; r < 4; ++r) {
    int n = n0 + wave * 16 + kgrp * 4 + r;
    dg[r] = (float)deg[n < N ? n : N - 1];
  }
#pragma unroll
  for (int c = 0; c < 8; ++c) {
    int col = c * 16 + rit;
    float bev = be[col], brv = br[col];
#pragma unroll
    for (int r = 0; r < 4; ++r) {
      float v = acc[c][r] + dg[r] * bev + brv;
      st[wave * 16 + kgrp * 4 + r][col] = f2bf(fmaxf(v, 0.f));
    }
  }
  if (POOL && t < 64) {
    int n = n0 + t;
    bsh[t] = (n < N) ? batch[n] : -1;
  }
  __syncthreads();

  if (POOL) {
    // sorted-batch run-length pooling over this block's 64 rows
    if (t < 128) {
      int c = t;
      float acc2 = 0.f;
      int g = bsh[0];
      for (int r = 0; r < 64; ++r) {
        int n = n0 + r;
        if (n >= N) break;
        int gn = bsh[r];
        if (gn != g) {
          atomicAdd(&pout[g * 128 + c], acc2);
          acc2 = 0.f;
          g = gn;
        }
        acc2 += bf2f(st[r][c]);
      }
      atomicAdd(&pout[g * 128 + c], acc2);
    }
  } else {
#pragma unroll
    for (int it = 0; it < 4; ++it) {
      int idx = t + it * 256;
      int row = idx >> 4, cg = idx & 15;
      int n = n0 + row;
      if (n < N)
        *(short8v*)(out + (size_t)n * 128 + cg * 8) = *(const short8v*)(&st[row][cg * 8]);
    }
  }
}

// ---------------- launch ----------------

extern "C" void kernel_launch(void* const* d_in, const int* in_sizes, int n_in,
                              void* d_out, int out_size, void* d_ws, size_t ws_size,
                              hipStream_t stream) {
  const float* x_in       = (const float*)d_in[0];
  const int*   edge_index = (const int*)d_in[1];
  const float* edge_attr  = (const float*)d_in[2];
  const int*   batch      = (const int*)d_in[3];
  const float* We0 = (const float*)d_in[4];
  const float* be0 = (const float*)d_in[5];
  const float* Wr0 = (const float*)d_in[6];
  const float* br0 = (const float*)d_in[7];
  const float* We1 = (const float*)d_in[8];
  const float* be1 = (const float*)d_in[9];
  const float* Wr1 = (const float*)d_in[10];
  const float* br1 = (const float*)d_in[11];
  const float* We2 = (const float*)d_in[12];
  const float* be2 = (const float*)d_in[13];
  const float* Wr2 = (const float*)d_in[14];
  const float* br2 = (const float*)d_in[15];

  float* out = (float*)d_out;

  int N = in_sizes[0] / 64;   // 50000
  int E = in_sizes[1] / 2;    // 1600000
  const int* src = edge_index;
  const int* dst = edge_index + E;

  char* w = (char*)d_ws;
  size_t off = 0;
  auto alloc = [&](size_t bytes) {
    void* p = w + off;
    off += (bytes + 255) & ~(size_t)255;
    return p;
  };
  int* deg   = (int*)alloc((size_t)N * 4);
  int* cnt   = (int*)alloc((size_t)N * 4);
  size_t zero_bytes = off;  // deg + cnt zeroed each call
  int* ptrs  = (int*)alloc((size_t)(N + 1) * 4);
  int* bsum  = (int*)alloc(128 * 4);
  int* boffs = (int*)alloc(128 * 4);
  int2* csr  = (int2*)alloc((size_t)E * 8);
  unsigned short* x_bf   = (unsigned short*)alloc((size_t)N * 64 * 2);
  unsigned short* aggx64 = (unsigned short*)alloc((size_t)N * 64 * 2);
  unsigned short* agge   = (unsigned short*)alloc((size_t)N * 64 * 2);
  unsigned short* aggx   = (unsigned short*)alloc((size_t)N * 128 * 2);
  unsigned short* xb0    = (unsigned short*)alloc((size_t)N * 128 * 2);
  unsigned short* xb1    = (unsigned short*)alloc((size_t)N * 128 * 2);
  unsigned short* Wt0    = (unsigned short*)alloc((size_t)128 * 192 * 2);
  unsigned short* Wt1    = (unsigned short*)alloc((size_t)128 * 320 * 2);
  unsigned short* Wt2    = (unsigned short*)alloc((size_t)128 * 320 * 2);

  (void)hipMemsetAsync(d_ws, 0, zero_bytes, stream);
  (void)hipMemsetAsync(d_out, 0, (size_t)out_size * sizeof(float), stream);

  int eb = (E + 255) / 256;
  int sb = (N + 511) / 512;
  count_deg_kernel<<<eb, 256, 0, stream>>>(dst, deg, E);
  block_sum_kernel<<<sb, 512, 0, stream>>>(deg, bsum, N);
  scan_small_kernel<<<1, 128, 0, stream>>>(bsum, boffs, sb);
  ptrs_kernel<<<sb, 512, 0, stream>>>(deg, boffs, ptrs, N);
  fill_csr_kernel<<<eb, 256, 0, stream>>>(src, dst, ptrs, cnt, csr, E);

  // conversions (independent of CSR)
  f2bf_stream_kernel<<<(N * 64 / 8 + 255) / 256, 256, 0, stream>>>(x_in, x_bf, N * 64);
  {
    int total = 128 * 192 + 2 * 128 * 320;
    pack_all_kernel<<<(total + 255) / 256, 256, 0, stream>>>(We0, Wr0, We1, Wr1, We2, Wr2,
                                                             Wt0, Wt1, Wt2);
  }

  int gb = (N + 63) / 64;
  int ab = (N + 3) / 4;

  // Layer-0 aggregation: edge_attr (layer-invariant) + x, one CSR pass
  agg0_kernel<<<ab, 256, 0, stream>>>(ptrs, csr, edge_attr, x_bf, agge, aggx64, N);

  // Layer 0: K-order (aggx64:We0[0:64], agge:We0[64:128], x:Wr0)
  gemm_mfma_kernel<0><<<gb, 256, 0, stream>>>(aggx64, 64, 64, agge, 64, 64, x_bf, 64, 64,
                                              Wt0, 192, be0, br0, deg, batch, xb0, nullptr, N);
  // Layer 1
  agg_bf128_kernel<<<ab, 256, 0, stream>>>(ptrs, csr, xb0, aggx, N);
  gemm_mfma_kernel<0><<<gb, 256, 0, stream>>>(aggx, 128, 128, agge, 64, 64, xb0, 128, 128,
                                              Wt1, 320, be1, br1, deg, batch, xb1, nullptr, N);
  // Layer 2 + fused readout pooling
  agg_bf128_kernel<<<ab, 256, 0, stream>>>(ptrs, csr, xb1, aggx, N);
  gemm_mfma_kernel<1><<<gb, 256, 0, stream>>>(aggx, 128, 128, agge, 64, 64, xb1, 128, 128,
                                              Wt2, 320, be2, br2, deg, batch, nullptr, out, N);
}